// Round 10
// baseline (908.219 us; speedup 1.0000x reference)
//
#include <hip/hip_runtime.h>
#include <hip/hip_bf16.h>
#include <hip/hip_cooperative_groups.h>

namespace cg = cooperative_groups;

// All float tensors are fp32. R8 lesson: entity gathers MUST stay fp32
// (v^2->exp logit chain amplifies bf16 quantization to absmax 5.3).

#define DD 64
#define KK 20
#define NCHUNK 313        // ceil(10000/32) 32-news chunks
#define NSL 20            // news slices
#define NSTRIP 157        // 64-user strips / 4 MFMA tiles per wave (proven R4 shape)
#define ATSTRIDE 10016    // padded news stride of d-major V (interleaved 32-blocks)
#define PST32 20          // P LDS row stride in u32 (80 B)

#define NUC 10000
#define NNC 10000
#define NEC 100000
#define NNZC 500000

// ---- cooperative mega-kernel phase geometry ----
#define GRID_MEGA 768     // 3 blocks/CU guaranteed by __launch_bounds__(256,3)
#define A_NEWS 1250
#define A_CVTU 628        // 643072/4/256
#define A_HIST 512
#define A_TOTAL (A_NEWS + A_CVTU + A_HIST)
#define B_TOTAL 80        // 79 transpose + 1 scan
#define C_FILL 512
#define D_ATTN 785        // 157*20/4
#define D_GATHER 2500
#define D_ENT 12500
#define D_TOTAL (D_ATTN + D_GATHER + D_ENT)
#define E_FINAL 625       // 640000/4/256

typedef __attribute__((ext_vector_type(8))) short short8;
typedef __attribute__((ext_vector_type(4))) float f32x4;

__device__ __forceinline__ unsigned short f2bf(float x) {
    union { __hip_bfloat16 h; unsigned short u; } cv;
    cv.h = __float2bfloat16(x);
    return cv.u;
}
__device__ __forceinline__ float bfu2f(unsigned short u) {
    return __uint_as_float(((unsigned)u) << 16);
}
#define MFMA16(a, b, c) __builtin_amdgcn_mfma_f32_16x16x32_bf16((a), (b), (c), 0, 0, 0)

// ---------------- aggregation body (news & entity), R2-proven shape ----------
// TWO rows per wave: lanes 0-31 = row n0, lanes 32-63 = row n0+1; lane holds
// d = {2l, 2l+1} as float2. FP32 gathers only (R8 accuracy lesson).
__device__ __forceinline__
void agg_body(const float* __restrict__ head_emb, const float* __restrict__ ent_emb,
              const float* __restrict__ rel_emb,
              const int* __restrict__ ent_idx, const int* __restrict__ rel_idx,
              float* __restrict__ outp, int bid)
{
    int w = threadIdx.x >> 6;
    int lane = threadIdx.x & 63;
    int half = lane >> 5;
    int l = lane & 31;
    int n0 = bid * 8 + w * 2;

    float2 head = *(const float2*)(head_emb + (long)(n0 + half) * DD + 2 * l);

    float2 tail[KK], trp[KK];
    float2 s2 = make_float2(0.f, 0.f);
#pragma unroll
    for (int k = 0; k < KK; ++k) {
        int ei0 = ent_idx[n0 * KK + k];
        int ei1 = ent_idx[(n0 + 1) * KK + k];
        int ri0 = rel_idx[n0 * KK + k];
        int ri1 = rel_idx[(n0 + 1) * KK + k];
        int e = half ? ei1 : ei0;
        int r = half ? ri1 : ri0;
        float2 rv = *(const float2*)(rel_emb + (long)r * DD + 2 * l);
        float2 tv = *(const float2*)(ent_emb + (long)e * DD + 2 * l);
        tail[k] = tv;
        trp[k] = make_float2(tv.x * rv.x, tv.y * rv.y);
        s2.x = fmaf(rv.x, rv.x, s2.x);
        s2.y = fmaf(rv.y, rv.y, s2.y);
    }
    float2 hn;
    hn.x = fabsf(head.x) * sqrtf(s2.x);
    hn.y = fabsf(head.y) * sqrtf(s2.y);

    float att[KK];
#pragma unroll
    for (int k = 0; k < KK; ++k) {
        float v = fmaf(trp[k].y, hn.y, trp[k].x * hn.x);
#pragma unroll
        for (int m = 1; m < 32; m <<= 1)
            v += __shfl_xor(v, m, 64);
        att[k] = v * v;
    }
    float mx = att[0];
#pragma unroll
    for (int k = 1; k < KK; ++k) mx = fmaxf(mx, att[k]);
    float den = 0.f;
#pragma unroll
    for (int k = 0; k < KK; ++k) { att[k] = __expf(att[k] - mx); den += att[k]; }
    float inv = 1.f / den;
    float2 o = make_float2(0.f, 0.f);
#pragma unroll
    for (int k = 0; k < KK; ++k) {
        o.x = fmaf(att[k], tail[k].x, o.x);
        o.y = fmaf(att[k], tail[k].y, o.y);
    }
    o.x *= inv; o.y *= inv;
    *(float2*)(outp + (long)(n0 + half) * DD + 2 * l) = o;
}

// ---------------- transpose + B-convert body (one 128-news stripe) ----------
__device__ __forceinline__
void transpose_body(int vb, const float* __restrict__ src,
                    unsigned short* __restrict__ Bbf, unsigned short* __restrict__ AT,
                    float (*T)[65])
{
    int t = threadIdx.x;
    int nb = vb * 128;
    const float4* s4 = (const float4*)src;
#pragma unroll
    for (int i = 0; i < 8; ++i) {
        int f = i * 256 + t;
        int row = f >> 4;
        int c4 = f & 15;
        int gr = nb + row;
        float4 v = make_float4(0.f, 0.f, 0.f, 0.f);
        if (gr < NNC) v = s4[(long)gr * 16 + c4];
        T[row][c4 * 4 + 0] = v.x;
        T[row][c4 * 4 + 1] = v.y;
        T[row][c4 * 4 + 2] = v.z;
        T[row][c4 * 4 + 3] = v.w;
    }
    __syncthreads();
    // B rows (bf16 row-major, pad to 10016)
#pragma unroll
    for (int i = 0; i < 8; ++i) {
        int f = i * 256 + t;
        int row = f >> 4;
        int q4 = f & 15;
        int gr = nb + row;
        if (gr < ATSTRIDE) {
            ushort4 ob;
            ob.x = f2bf(T[row][q4 * 4 + 0]);
            ob.y = f2bf(T[row][q4 * 4 + 1]);
            ob.z = f2bf(T[row][q4 * 4 + 2]);
            ob.w = f2bf(T[row][q4 * 4 + 3]);
            *(ushort4*)(Bbf + (long)gr * 64 + q4 * 4) = ob;
        }
    }
    // AT interleaved: map {2g, 16+2g, 2g+1, 16+2g+1} within each 32-block
    int d = t >> 2;
    int seg = t & 3;
#pragma unroll
    for (int g = 0; g < 8; ++g) {
        int nl = seg * 32 + g * 4;
        int n = nb + nl;
        if (n + 3 < ATSTRIDE) {
            int base = seg * 32;
            ushort4 oh;
            oh.x = f2bf(T[base + 2 * g][d]);
            oh.y = f2bf(T[base + 16 + 2 * g][d]);
            oh.z = f2bf(T[base + 2 * g + 1][d]);
            oh.w = f2bf(T[base + 16 + 2 * g + 1][d]);
            *(ushort4*)(AT + (long)d * ATSTRIDE + n) = oh;
        }
    }
    __syncthreads();   // T reused only by this block; keep symmetric
}

// ---------------- scan body (single 256-thread block) ------------------------
__device__ __forceinline__
void scan_body(const int* __restrict__ cnt, int* __restrict__ offs,
               int* __restrict__ cur, int* __restrict__ ssum)
{
    int t = threadIdx.x;
    int loc[40];
    int s = 0;
#pragma unroll
    for (int i = 0; i < 40; ++i) { loc[i] = s; s += cnt[t * 40 + i]; }
    ssum[t] = s;
    __syncthreads();
    int val = s;
    for (int off = 1; off < 256; off <<= 1) {
        int v = (t >= off) ? ssum[t - off] : 0;
        __syncthreads();
        val += v;
        ssum[t] = val;
        __syncthreads();
    }
    int excl = val - s;
#pragma unroll
    for (int i = 0; i < 40; ++i) {
        int o = excl + loc[i];
        offs[t * 40 + i] = o;
        cur[t * 40 + i] = o;
    }
}

// ---------------- gather body: unroll-4 (4 edge-chains in flight) ------------
__device__ __forceinline__
void gather_body(int vb, const int* __restrict__ offs, const int* __restrict__ eid,
                 const int* __restrict__ cols, const float* __restrict__ vals,
                 const float* __restrict__ A, float* __restrict__ seg)
{
    int w = threadIdx.x >> 6;
    int lane = threadIdx.x & 63;
    int u = vb * 4 + w;                 // vb < 2500 -> u < 10000 always
    int s0 = offs[u], s1 = offs[u + 1];
    float a0 = 0.f, a1 = 0.f, a2 = 0.f, a3 = 0.f;
    int i = s0;
    for (; i + 3 < s1; i += 4) {
        int e0 = eid[i], e1 = eid[i + 1], e2 = eid[i + 2], e3 = eid[i + 3];
        float v0 = vals[e0], v1 = vals[e1], v2 = vals[e2], v3 = vals[e3];
        int c0 = cols[e0], c1 = cols[e1], c2 = cols[e2], c3 = cols[e3];
        a0 = fmaf(v0, A[(long)c0 * DD + lane], a0);
        a1 = fmaf(v1, A[(long)c1 * DD + lane], a1);
        a2 = fmaf(v2, A[(long)c2 * DD + lane], a2);
        a3 = fmaf(v3, A[(long)c3 * DD + lane], a3);
    }
    for (; i < s1; ++i) {
        int e = eid[i];
        a0 = fmaf(vals[e], A[(long)cols[e] * DD + lane], a0);
    }
    seg[(long)u * DD + lane] = (a0 + a1) + (a2 + a3);
}

// ---------------- attn body: R4-proven (98.9us), 64 users/wave ---------------
__device__ __forceinline__
void attn_body(const unsigned short* __restrict__ Ubf,
               const unsigned short* __restrict__ Bbf,
               const unsigned short* __restrict__ ATbf,
               float* __restrict__ num, float* __restrict__ den,
               unsigned int* __restrict__ PuAll, int bid)
{
    int w = threadIdx.x >> 6;
    int lane = threadIdx.x & 63;
    int quad = lane >> 4;
    int l15 = lane & 15;
    int wid = bid * 4 + w;
    int strip = wid % NSTRIP;
    int slice = wid / NSTRIP;
    int user0 = strip * 64;

    short8 ua0[4], ua1[4];
#pragma unroll
    for (int t = 0; t < 4; ++t) {
        const short* up = (const short*)Ubf + ((long)(user0 + t * 16 + l15)) * 64;
        ua0[t] = *(const short8*)(up + quad * 8);
        ua1[t] = *(const short8*)(up + 32 + quad * 8);
    }

    f32x4 numC[4][4];
    float dena[4][4];
#pragma unroll
    for (int t = 0; t < 4; ++t)
#pragma unroll
        for (int c = 0; c < 4; ++c) {
            numC[t][c] = (f32x4){0.f, 0.f, 0.f, 0.f};
            dena[t][c] = 0.f;
        }

    for (int ch = slice; ch < NCHUNK; ch += NSL) {
        int nb = ch * 32;
        const short* bh = (const short*)Bbf + ((long)(nb + l15)) * 64;
        short8 b00 = *(const short8*)(bh + quad * 8);
        short8 b01 = *(const short8*)(bh + 32 + quad * 8);
        short8 b10 = *(const short8*)(bh + 16 * 64 + quad * 8);
        short8 b11 = *(const short8*)(bh + 16 * 64 + 32 + quad * 8);

        short8 vh[4];
#pragma unroll
        for (int c = 0; c < 4; ++c)
            vh[c] = *(const short8*)((const short*)ATbf +
                    ((long)(16 * c + l15)) * ATSTRIDE + nb + quad * 8);

        bool vlo = (nb + l15) < NNC;
        bool vhi = (nb + 16 + l15) < NNC;
        f32x4 z = {0.f, 0.f, 0.f, 0.f};
#pragma unroll
        for (int p = 0; p < 2; ++p) {
#pragma unroll
            for (int tt = 0; tt < 2; ++tt) {
                int t = p * 2 + tt;
                f32x4 Llo = MFMA16(ua0[t], b00, z);
                Llo = MFMA16(ua1[t], b01, Llo);
                f32x4 Lhi = MFMA16(ua0[t], b10, z);
                Lhi = MFMA16(ua1[t], b11, Lhi);
                unsigned int* Pt = PuAll + (w * 2 + tt) * (16 * PST32);
#pragma unroll
                for (int r = 0; r < 4; ++r) {
                    float plo = vlo ? __expf(fminf(Llo[r], 70.f)) : 0.f;
                    float phi = vhi ? __expf(fminf(Lhi[r], 70.f)) : 0.f;
                    __hip_bfloat162 pk2 = __float22bfloat162_rn(make_float2(plo, phi));
                    unsigned int pk;
                    __builtin_memcpy(&pk, &pk2, 4);
                    Pt[(quad * 4 + r) * PST32 + l15] = pk;
                    dena[t][r] += __uint_as_float(pk << 16)
                                + __uint_as_float(pk & 0xffff0000u);
                }
            }
            short8 ap[2];
#pragma unroll
            for (int tt = 0; tt < 2; ++tt)
                ap[tt] = *(const short8*)((const short*)(PuAll + (w * 2 + tt) * (16 * PST32)) +
                         l15 * (PST32 * 2) + quad * 8);
#pragma unroll
            for (int c = 0; c < 4; ++c)
#pragma unroll
                for (int tt = 0; tt < 2; ++tt)
                    numC[p * 2 + tt][c] = MFMA16(ap[tt], vh[c], numC[p * 2 + tt][c]);
        }
    }

#pragma unroll
    for (int t = 0; t < 4; ++t)
#pragma unroll
        for (int r = 0; r < 4; ++r) {
#pragma unroll
            for (int m = 1; m < 16; m <<= 1)
                dena[t][r] += __shfl_xor(dena[t][r], m, 64);
        }
    if (l15 == 0) {
#pragma unroll
        for (int t = 0; t < 4; ++t)
#pragma unroll
            for (int r = 0; r < 4; ++r)
                atomicAdd(&den[user0 + t * 16 + quad * 4 + r], dena[t][r]);
    }
#pragma unroll
    for (int t = 0; t < 4; ++t)
#pragma unroll
        for (int c = 0; c < 4; ++c)
#pragma unroll
            for (int r = 0; r < 4; ++r)
                atomicAdd(&num[(long)(user0 + t * 16 + quad * 4 + r) * DD + c * 16 + l15],
                          numC[t][c][r]);
}

// =================== R10: single cooperative persistent kernel ===============
// 768 blocks (3/CU guaranteed: launch_bounds(256,3) caps VGPR ~168 >= attn's
// ~100; LDS 33.3KB*3 < 160KB). Phases separated by grid.sync(); phase D is
// dynamically scheduled (global atomic ctr, longest-job-first: attn->gather->
// ent) so the three latency-bound workloads pack every slot. Replaces 6
// launches + memset (~85us of node overhead measured at ~14us/node, R4->R6).
__global__ __launch_bounds__(256, 3)
void mega_kernel(const float* __restrict__ user_emb, const float* __restrict__ news_emb,
                 const float* __restrict__ ent_emb, const float* __restrict__ rel_emb,
                 const int* __restrict__ news_entities, const int* __restrict__ news_relations,
                 const int* __restrict__ neigh_entities, const int* __restrict__ neigh_relations,
                 const int* __restrict__ interact_rows, const int* __restrict__ interact_cols,
                 const float* __restrict__ interact_vals,
                 float* __restrict__ out_news, float* __restrict__ out_ent,
                 float* __restrict__ out_user, float* __restrict__ base)
{
    // scratch layout (matches launcher)
    float* seg  = base;
    float* num  = seg + 640000;
    float* den  = num + 643072;
    int*   cnt  = (int*)(den + 10240);
    int*   offs = cnt + 10240;
    int*   cur  = offs + 10240;
    int*   eid  = cur + 10240;
    unsigned short* Ubf  = (unsigned short*)(eid + 500000);
    unsigned short* Bbf  = Ubf + 643072;
    unsigned short* ATbf = Bbf + 641024;
    int* wctr = (int*)(ATbf + 641024);

    __shared__ __align__(16) char smem[33280];   // union: T[128][65] | Pu | ssum
    __shared__ int s_vb;

    cg::grid_group grid = cg::this_grid();
    int bid = blockIdx.x;
    int tid = threadIdx.x;

    // ---- phase 0: zero num|den|cnt (contiguous 663552 f32) + work counter ----
    for (int i = bid * 256 + tid; i < 643072 + 10240 + 10240; i += GRID_MEGA * 256)
        num[i] = 0.f;
    if (bid == 0 && tid == 0) atomicExch(wctr, 0);
    grid.sync();

    // ---- phase A: news agg | cvt U | hist ----
    for (int vb = bid; vb < A_TOTAL; vb += GRID_MEGA) {
        if (vb < A_NEWS) {
            agg_body(news_emb, ent_emb, rel_emb,
                     news_entities, news_relations, out_news, vb);
        } else if (vb < A_NEWS + A_CVTU) {
            int i = (vb - A_NEWS) * 256 + tid;
            int bse = i * 4;
            float4 v = make_float4(0.f, 0.f, 0.f, 0.f);
            if (bse + 3 < NUC * DD) v = *(const float4*)(user_emb + bse);
            ushort4 o;
            o.x = f2bf(v.x); o.y = f2bf(v.y); o.z = f2bf(v.z); o.w = f2bf(v.w);
            *(ushort4*)(Ubf + bse) = o;
        } else {
            int lb = vb - (A_NEWS + A_CVTU);
            for (int e = lb * 256 + tid; e < NNZC; e += A_HIST * 256)
                atomicAdd(&cnt[interact_rows[e]], 1);
        }
    }
    grid.sync();

    // ---- phase B: transpose+Bcvt (79) | scan (1) ----
    for (int vb = bid; vb < B_TOTAL; vb += GRID_MEGA) {
        if (vb < 79)
            transpose_body(vb, out_news, Bbf, ATbf, (float(*)[65])smem);
        else
            scan_body(cnt, offs, cur, (int*)smem);
    }
    grid.sync();

    // ---- phase C: fill ----
    for (int vb = bid; vb < C_FILL; vb += GRID_MEGA) {
        for (int e = vb * 256 + tid; e < NNZC; e += C_FILL * 256) {
            int p = atomicAdd(&cur[interact_rows[e]], 1);
            eid[p] = e;
        }
    }
    grid.sync();

    // ---- phase D: attn | gather | entity agg -- dynamic, longest-first ----
    for (;;) {
        if (tid == 0) s_vb = atomicAdd(wctr, 1);
        __syncthreads();
        int vb = s_vb;
        __syncthreads();
        if (vb >= D_TOTAL) break;
        if (vb < D_ATTN) {
            attn_body(Ubf, Bbf, ATbf, num, den, (unsigned int*)smem, vb);
        } else if (vb < D_ATTN + D_GATHER) {
            gather_body(vb - D_ATTN, offs, eid, interact_cols, interact_vals,
                        out_news, seg);
        } else {
            agg_body(ent_emb, ent_emb, rel_emb, neigh_entities, neigh_relations,
                     out_ent, vb - (D_ATTN + D_GATHER));
        }
    }
    grid.sync();

    // ---- phase E: final combine (float4) ----
    for (int vb = bid; vb < E_FINAL; vb += GRID_MEGA) {
        int bse = (vb * 256 + tid) * 4;
        int u = bse >> 6;
        float dv = den[u];
        float4 s = *(const float4*)(seg + bse);
        float4 n = *(const float4*)(num + bse);
        float4 o;
        o.x = fmaf(s.x, n.x / dv, s.x);
        o.y = fmaf(s.y, n.y / dv, s.y);
        o.z = fmaf(s.z, n.z / dv, s.z);
        o.w = fmaf(s.w, n.w / dv, s.w);
        *(float4*)(out_user + bse) = o;
    }
}

// =================== fallback path: R9's 6-kernel sequence ===================
__global__ __launch_bounds__(256)
void k1_kernel(const float* __restrict__ news_emb, const float* __restrict__ ent_emb,
               const float* __restrict__ rel_emb,
               const int* __restrict__ news_entities, const int* __restrict__ news_relations,
               float* __restrict__ out_news,
               const float* __restrict__ user_emb, unsigned short* __restrict__ Ubf,
               const int* __restrict__ irows, int* __restrict__ cnt)
{
    int bid = blockIdx.x;
    if (bid < A_NEWS) {
        agg_body(news_emb, ent_emb, rel_emb, news_entities, news_relations, out_news, bid);
    } else if (bid < A_NEWS + A_CVTU) {
        int i = (bid - A_NEWS) * 256 + threadIdx.x;
        int bse = i * 4;
        float4 v = make_float4(0.f, 0.f, 0.f, 0.f);
        if (bse + 3 < NUC * DD) v = *(const float4*)(user_emb + bse);
        ushort4 o;
        o.x = f2bf(v.x); o.y = f2bf(v.y); o.z = f2bf(v.z); o.w = f2bf(v.w);
        *(ushort4*)(Ubf + bse) = o;
    } else {
        int lb = bid - (A_NEWS + A_CVTU);
        for (int e = lb * 256 + threadIdx.x; e < NNZC; e += A_HIST * 256)
            atomicAdd(&cnt[irows[e]], 1);
    }
}

__global__ __launch_bounds__(256)
void k2_kernel(const float* __restrict__ src, unsigned short* __restrict__ Bbf,
               unsigned short* __restrict__ AT,
               const int* __restrict__ cnt, int* __restrict__ offs, int* __restrict__ cur)
{
    __shared__ __align__(16) char smem[33280];
    if (blockIdx.x < 79)
        transpose_body(blockIdx.x, src, Bbf, AT, (float(*)[65])smem);
    else
        scan_body(cnt, offs, cur, (int*)smem);
}

__global__ __launch_bounds__(256)
void k3_kernel(const unsigned short* __restrict__ Ubf,
               const unsigned short* __restrict__ Bbf,
               const unsigned short* __restrict__ ATbf,
               float* __restrict__ num, float* __restrict__ den,
               const int* __restrict__ irows, int* __restrict__ cur,
               int* __restrict__ eid)
{
    __shared__ __align__(16) unsigned int Pu[8][16 * PST32];
    int bid = blockIdx.x;
    if (bid < D_ATTN) {
        attn_body(Ubf, Bbf, ATbf, num, den, &Pu[0][0], bid);
    } else {
        int lb = bid - D_ATTN;
        for (int e = lb * 256 + threadIdx.x; e < NNZC; e += C_FILL * 256) {
            int p = atomicAdd(&cur[irows[e]], 1);
            eid[p] = e;
        }
    }
}

__global__ __launch_bounds__(256)
void k4_kernel(const int* __restrict__ offs, const int* __restrict__ eid,
               const int* __restrict__ cols, const float* __restrict__ vals,
               const float* __restrict__ A, float* __restrict__ seg,
               const float* __restrict__ ent_emb, const float* __restrict__ rel_emb,
               const int* __restrict__ neigh_entities, const int* __restrict__ neigh_relations,
               float* __restrict__ out_ent, int ent_blocks)
{
    int bid = blockIdx.x;
    if (bid < D_GATHER) {
        gather_body(bid, offs, eid, cols, vals, A, seg);
    } else if (bid < D_GATHER + ent_blocks) {
        agg_body(ent_emb, ent_emb, rel_emb, neigh_entities, neigh_relations,
                 out_ent, bid - D_GATHER);
    }
}

__global__ __launch_bounds__(256)
void agg_ent_kernel(const float* __restrict__ ent_emb, const float* __restrict__ rel_emb,
                    const int* __restrict__ ent_idx, const int* __restrict__ rel_idx,
                    float* __restrict__ outp)
{
    agg_body(ent_emb, ent_emb, rel_emb, ent_idx, rel_idx, outp, blockIdx.x);
}

__global__ __launch_bounds__(256)
void final_kernel(const float* __restrict__ seg, const float* __restrict__ num,
                  const float* __restrict__ den, float* __restrict__ out, int n_users)
{
    int t = blockIdx.x * 256 + threadIdx.x;
    if (t >= n_users * DD) return;
    int u = t >> 6;
    float s = seg[t];
    float o2 = num[t] / den[u];
    out[t] = fmaf(s, o2, s);
}

extern "C" void kernel_launch(void* const* d_in, const int* in_sizes, int n_in,
                              void* d_out, int out_size, void* d_ws, size_t ws_size,
                              hipStream_t stream)
{
    const float* user_emb = (const float*)d_in[0];
    const float* news_emb = (const float*)d_in[1];
    const float* ent_emb  = (const float*)d_in[2];
    const float* rel_emb  = (const float*)d_in[3];
    const int* news_entities   = (const int*)d_in[4];
    const int* news_relations  = (const int*)d_in[5];
    const int* neigh_entities  = (const int*)d_in[6];
    const int* neigh_relations = (const int*)d_in[7];
    const int* interact_rows   = (const int*)d_in[8];
    const int* interact_cols   = (const int*)d_in[9];
    const float* interact_vals = (const float*)d_in[10];

    const int NU = 10000, NN = 10000, NE = 100000;

    float* out_news = (float*)d_out;
    float* out_ent  = out_news + (long)NN * DD;
    float* out_user = out_ent + (long)NE * DD;

    // Scratch ~11.15 MB (+64B work counter): prefer d_ws, fall back to out_ent
    const size_t BASIC_BYTES =
        (size_t)(640000 + 643072 + 10240 + 10240 + 10240 + 10240 + 500000) * 4 +
        (size_t)(643072 + 641024 + 641024) * 2 + 64;

    bool use_ws = (d_ws != nullptr) && (ws_size >= BASIC_BYTES);
    float* base = use_ws ? (float*)d_ws : out_ent;

    float* seg  = base;
    float* num  = seg + 640000;
    float* den  = num + 643072;
    int*   cnt  = (int*)(den + 10240);
    int*   offs = cnt + 10240;
    int*   cur  = offs + 10240;
    int*   eid  = cur + 10240;
    unsigned short* Ubf  = (unsigned short*)(eid + 500000);
    unsigned short* Bbf  = Ubf + 643072;
    unsigned short* ATbf = Bbf + 641024;

    if (use_ws) {
        // ---- R10: single cooperative launch (zeroing done in-kernel) ----
        void* kargs[] = {
            (void*)&user_emb, (void*)&news_emb, (void*)&ent_emb, (void*)&rel_emb,
            (void*)&news_entities, (void*)&news_relations,
            (void*)&neigh_entities, (void*)&neigh_relations,
            (void*)&interact_rows, (void*)&interact_cols, (void*)&interact_vals,
            (void*)&out_news, (void*)&out_ent, (void*)&out_user, (void*)&base
        };
        hipError_t err = hipLaunchCooperativeKernel(
            reinterpret_cast<const void*>(mega_kernel),
            dim3(GRID_MEGA), dim3(256), kargs, 0, stream);
        if (err == hipSuccess) return;
        // else fall through to the proven R9 sequence
    }

    // ---- fallback: R9 6-node sequence ----
    hipMemsetAsync(num, 0, (size_t)(643072 + 10240 + 10240) * sizeof(float), stream);
    k1_kernel<<<A_TOTAL, 256, 0, stream>>>(news_emb, ent_emb, rel_emb,
                                           news_entities, news_relations, out_news,
                                           user_emb, Ubf, interact_rows, cnt);
    k2_kernel<<<B_TOTAL, 256, 0, stream>>>(out_news, Bbf, ATbf, cnt, offs, cur);
    k3_kernel<<<D_ATTN + C_FILL, 256, 0, stream>>>(Ubf, Bbf, ATbf, num, den,
                                                   interact_rows, cur, eid);
    if (use_ws) {
        k4_kernel<<<D_GATHER + D_ENT, 256, 0, stream>>>(
            offs, eid, interact_cols, interact_vals, out_news, seg,
            ent_emb, rel_emb, neigh_entities, neigh_relations, out_ent, D_ENT);
        final_kernel<<<(NU * DD + 255) / 256, 256, 0, stream>>>(seg, num, den, out_user, NU);
    } else {
        k4_kernel<<<D_GATHER, 256, 0, stream>>>(
            offs, eid, interact_cols, interact_vals, out_news, seg,
            ent_emb, rel_emb, neigh_entities, neigh_relations, out_ent, 0);
        final_kernel<<<(NU * DD + 255) / 256, 256, 0, stream>>>(seg, num, den, out_user, NU);
        agg_ent_kernel<<<NE / 8, 256, 0, stream>>>(ent_emb, rel_emb,
                                                   neigh_entities, neigh_relations, out_ent);
    }
}

// Round 11
// 456.027 us; speedup vs baseline: 1.9916x; 1.9916x over previous
//
#include <hip/hip_runtime.h>
#include <hip/hip_bf16.h>

// All float tensors are fp32. R8 lesson: entity gathers MUST stay fp32
// (v^2->exp logit chain amplifies bf16 quantization to absmax 5.3).
// R10 lesson: NEVER fold the attn body into a multi-body persistent kernel --
// the shared register frame (VGPR 84 < attn's ~100) spills the MFMA loop.

#define DD 64
#define KK 20
#define NCHUNK 313        // ceil(10000/32) 32-news chunks
#define NSL 20            // news slices
#define NSTRIP 157        // 64-user strips / 4 MFMA tiles per wave (proven R4 shape)
#define ATSTRIDE 10016    // padded news stride of d-major V (interleaved 32-blocks)
#define PST32 20          // P LDS row stride in u32 (80 B)

#define NUC 10000
#define NNC 10000
#define NEC 100000
#define NNZC 500000

// K1: news agg (16 rows/block) | cvt U | hist
#define K1_NEWS 625
#define K1_CVTU 628       // 643072/4/256
#define K1_HIST 512
#define K1_GRID (K1_NEWS + K1_CVTU + K1_HIST)
// K3: attn | fill
#define ATTN_BLOCKS 785   // 157*20/4
#define K3_FILL 512
#define K3_GRID (ATTN_BLOCKS + K3_FILL)
// K4: gather alone (R9 post-mortem: gather||ent thrashed L2 -> 205us superadditive)
#define K4_GATHER 2500
// K5: final | entity agg (16 rows/block)
#define K5_FINAL 625      // 640000 f32 = 625*256*4
#define K5_ENT 6250
#define K5_GRID (K5_FINAL + K5_ENT)

typedef __attribute__((ext_vector_type(8))) short short8;
typedef __attribute__((ext_vector_type(4))) float f32x4;

__device__ __forceinline__ unsigned short f2bf(float x) {
    union { __hip_bfloat16 h; unsigned short u; } cv;
    cv.h = __float2bfloat16(x);
    return cv.u;
}
__device__ __forceinline__ float bfu2f(unsigned short u) {
    return __uint_as_float(((unsigned)u) << 16);
}
#define MFMA16(a, b, c) __builtin_amdgcn_mfma_f32_16x16x32_bf16((a), (b), (c), 0, 0, 0)

// ---------------- aggregation body (8 rows per call), R2-proven shape --------
// TWO rows per wave: lanes 0-31 = row n0, lanes 32-63 = row n0+1; lane holds
// d = {2l, 2l+1} as float2. FP32 gathers only.
__device__ __forceinline__
void agg_body(const float* __restrict__ head_emb, const float* __restrict__ ent_emb,
              const float* __restrict__ rel_emb,
              const int* __restrict__ ent_idx, const int* __restrict__ rel_idx,
              float* __restrict__ outp, int bid)
{
    int w = threadIdx.x >> 6;
    int lane = threadIdx.x & 63;
    int half = lane >> 5;
    int l = lane & 31;
    int n0 = bid * 8 + w * 2;

    float2 head = *(const float2*)(head_emb + (long)(n0 + half) * DD + 2 * l);

    float2 tail[KK], trp[KK];
    float2 s2 = make_float2(0.f, 0.f);
#pragma unroll
    for (int k = 0; k < KK; ++k) {
        int ei0 = ent_idx[n0 * KK + k];
        int ei1 = ent_idx[(n0 + 1) * KK + k];
        int ri0 = rel_idx[n0 * KK + k];
        int ri1 = rel_idx[(n0 + 1) * KK + k];
        int e = half ? ei1 : ei0;
        int r = half ? ri1 : ri0;
        float2 rv = *(const float2*)(rel_emb + (long)r * DD + 2 * l);
        float2 tv = *(const float2*)(ent_emb + (long)e * DD + 2 * l);
        tail[k] = tv;
        trp[k] = make_float2(tv.x * rv.x, tv.y * rv.y);
        s2.x = fmaf(rv.x, rv.x, s2.x);
        s2.y = fmaf(rv.y, rv.y, s2.y);
    }
    float2 hn;
    hn.x = fabsf(head.x) * sqrtf(s2.x);
    hn.y = fabsf(head.y) * sqrtf(s2.y);

    float att[KK];
#pragma unroll
    for (int k = 0; k < KK; ++k) {
        float v = fmaf(trp[k].y, hn.y, trp[k].x * hn.x);
#pragma unroll
        for (int m = 1; m < 32; m <<= 1)
            v += __shfl_xor(v, m, 64);
        att[k] = v * v;
    }
    float mx = att[0];
#pragma unroll
    for (int k = 1; k < KK; ++k) mx = fmaxf(mx, att[k]);
    float den = 0.f;
#pragma unroll
    for (int k = 0; k < KK; ++k) { att[k] = __expf(att[k] - mx); den += att[k]; }
    float inv = 1.f / den;
    float2 o = make_float2(0.f, 0.f);
#pragma unroll
    for (int k = 0; k < KK; ++k) {
        o.x = fmaf(att[k], tail[k].x, o.x);
        o.y = fmaf(att[k], tail[k].y, o.y);
    }
    o.x *= inv; o.y *= inv;
    *(float2*)(outp + (long)(n0 + half) * DD + 2 * l) = o;
}

// ---------------- K1: news agg (16 rows/block) | cvt U | hist ----------------
__global__ __launch_bounds__(256)
void k1_kernel(const float* __restrict__ news_emb, const float* __restrict__ ent_emb,
               const float* __restrict__ rel_emb,
               const int* __restrict__ news_entities, const int* __restrict__ news_relations,
               float* __restrict__ out_news,
               const float* __restrict__ user_emb, unsigned short* __restrict__ Ubf,
               const int* __restrict__ irows, int* __restrict__ cnt)
{
    int bid = blockIdx.x;
    if (bid < K1_NEWS) {
        // 16 rows/block: halves dispatch count (uniform agg runs at ~127 WG/us,
        // 6us lifetime -> dispatch-bound; 2 sequential 8-row calls fix that
        // without R7's 1024-thread granularity trap)
        agg_body(news_emb, ent_emb, rel_emb, news_entities, news_relations,
                 out_news, 2 * bid);
        agg_body(news_emb, ent_emb, rel_emb, news_entities, news_relations,
                 out_news, 2 * bid + 1);
    } else if (bid < K1_NEWS + K1_CVTU) {
        int i = (bid - K1_NEWS) * 256 + threadIdx.x;
        int bse = i * 4;
        float4 v = make_float4(0.f, 0.f, 0.f, 0.f);
        if (bse + 3 < NUC * DD) v = *(const float4*)(user_emb + bse);
        ushort4 o;
        o.x = f2bf(v.x); o.y = f2bf(v.y); o.z = f2bf(v.z); o.w = f2bf(v.w);
        *(ushort4*)(Ubf + bse) = o;
    } else {
        int lb = bid - (K1_NEWS + K1_CVTU);
        for (int e = lb * 256 + threadIdx.x; e < NNZC; e += K1_HIST * 256)
            atomicAdd(&cnt[irows[e]], 1);
    }
}

// ---------------- K2: transpose+Bcvt (blocks 0..78) | scan (block 79) --------
__global__ __launch_bounds__(256)
void k2_kernel(const float* __restrict__ src, unsigned short* __restrict__ Bbf,
               unsigned short* __restrict__ AT,
               const int* __restrict__ cnt, int* __restrict__ offs, int* __restrict__ cur)
{
    __shared__ float T[128][65];
    __shared__ int ssum[256];
    int t = threadIdx.x;
    if (blockIdx.x < 79) {
        int nb = blockIdx.x * 128;
        const float4* s4 = (const float4*)src;
#pragma unroll
        for (int i = 0; i < 8; ++i) {
            int f = i * 256 + t;
            int row = f >> 4;
            int c4 = f & 15;
            int gr = nb + row;
            float4 v = make_float4(0.f, 0.f, 0.f, 0.f);
            if (gr < NNC) v = s4[(long)gr * 16 + c4];
            T[row][c4 * 4 + 0] = v.x;
            T[row][c4 * 4 + 1] = v.y;
            T[row][c4 * 4 + 2] = v.z;
            T[row][c4 * 4 + 3] = v.w;
        }
        __syncthreads();
        // B rows (bf16 row-major, pad to 10016)
#pragma unroll
        for (int i = 0; i < 8; ++i) {
            int f = i * 256 + t;
            int row = f >> 4;
            int q4 = f & 15;
            int gr = nb + row;
            if (gr < ATSTRIDE) {
                ushort4 ob;
                ob.x = f2bf(T[row][q4 * 4 + 0]);
                ob.y = f2bf(T[row][q4 * 4 + 1]);
                ob.z = f2bf(T[row][q4 * 4 + 2]);
                ob.w = f2bf(T[row][q4 * 4 + 3]);
                *(ushort4*)(Bbf + (long)gr * 64 + q4 * 4) = ob;
            }
        }
        // AT interleaved: map {2g, 16+2g, 2g+1, 16+2g+1} within each 32-block
        int d = t >> 2;
        int seg = t & 3;
#pragma unroll
        for (int g = 0; g < 8; ++g) {
            int nl = seg * 32 + g * 4;
            int n = nb + nl;
            if (n + 3 < ATSTRIDE) {
                int base = seg * 32;
                ushort4 oh;
                oh.x = f2bf(T[base + 2 * g][d]);
                oh.y = f2bf(T[base + 16 + 2 * g][d]);
                oh.z = f2bf(T[base + 2 * g + 1][d]);
                oh.w = f2bf(T[base + 16 + 2 * g + 1][d]);
                *(ushort4*)(AT + (long)d * ATSTRIDE + n) = oh;
            }
        }
    } else {
        // scan: 256 threads x 40 rows = 10240 >= 10001 needed
        int loc[40];
        int s = 0;
#pragma unroll
        for (int i = 0; i < 40; ++i) { loc[i] = s; s += cnt[t * 40 + i]; }
        ssum[t] = s;
        __syncthreads();
        int val = s;
        for (int off = 1; off < 256; off <<= 1) {
            int v = (t >= off) ? ssum[t - off] : 0;
            __syncthreads();
            val += v;
            ssum[t] = val;
            __syncthreads();
        }
        int excl = val - s;
#pragma unroll
        for (int i = 0; i < 40; ++i) {
            int o = excl + loc[i];
            offs[t * 40 + i] = o;
            cur[t * 40 + i] = o;
        }
    }
}

// ---------------- attn body: R4-proven (98.9us), 64 users/wave ---------------
__device__ __forceinline__
void attn_body(const unsigned short* __restrict__ Ubf,
               const unsigned short* __restrict__ Bbf,
               const unsigned short* __restrict__ ATbf,
               float* __restrict__ num, float* __restrict__ den,
               unsigned int* __restrict__ PuAll, int bid)
{
    int w = threadIdx.x >> 6;
    int lane = threadIdx.x & 63;
    int quad = lane >> 4;
    int l15 = lane & 15;
    int wid = bid * 4 + w;
    int strip = wid % NSTRIP;
    int slice = wid / NSTRIP;
    int user0 = strip * 64;

    short8 ua0[4], ua1[4];
#pragma unroll
    for (int t = 0; t < 4; ++t) {
        const short* up = (const short*)Ubf + ((long)(user0 + t * 16 + l15)) * 64;
        ua0[t] = *(const short8*)(up + quad * 8);
        ua1[t] = *(const short8*)(up + 32 + quad * 8);
    }

    f32x4 numC[4][4];
    float dena[4][4];
#pragma unroll
    for (int t = 0; t < 4; ++t)
#pragma unroll
        for (int c = 0; c < 4; ++c) {
            numC[t][c] = (f32x4){0.f, 0.f, 0.f, 0.f};
            dena[t][c] = 0.f;
        }

    for (int ch = slice; ch < NCHUNK; ch += NSL) {
        int nb = ch * 32;
        const short* bh = (const short*)Bbf + ((long)(nb + l15)) * 64;
        short8 b00 = *(const short8*)(bh + quad * 8);
        short8 b01 = *(const short8*)(bh + 32 + quad * 8);
        short8 b10 = *(const short8*)(bh + 16 * 64 + quad * 8);
        short8 b11 = *(const short8*)(bh + 16 * 64 + 32 + quad * 8);

        short8 vh[4];
#pragma unroll
        for (int c = 0; c < 4; ++c)
            vh[c] = *(const short8*)((const short*)ATbf +
                    ((long)(16 * c + l15)) * ATSTRIDE + nb + quad * 8);

        bool vlo = (nb + l15) < NNC;
        bool vhi = (nb + 16 + l15) < NNC;
        f32x4 z = {0.f, 0.f, 0.f, 0.f};
#pragma unroll
        for (int p = 0; p < 2; ++p) {
#pragma unroll
            for (int tt = 0; tt < 2; ++tt) {
                int t = p * 2 + tt;
                f32x4 Llo = MFMA16(ua0[t], b00, z);
                Llo = MFMA16(ua1[t], b01, Llo);
                f32x4 Lhi = MFMA16(ua0[t], b10, z);
                Lhi = MFMA16(ua1[t], b11, Lhi);
                unsigned int* Pt = PuAll + (w * 2 + tt) * (16 * PST32);
#pragma unroll
                for (int r = 0; r < 4; ++r) {
                    float plo = vlo ? __expf(fminf(Llo[r], 70.f)) : 0.f;
                    float phi = vhi ? __expf(fminf(Lhi[r], 70.f)) : 0.f;
                    __hip_bfloat162 pk2 = __float22bfloat162_rn(make_float2(plo, phi));
                    unsigned int pk;
                    __builtin_memcpy(&pk, &pk2, 4);
                    Pt[(quad * 4 + r) * PST32 + l15] = pk;
                    dena[t][r] += __uint_as_float(pk << 16)
                                + __uint_as_float(pk & 0xffff0000u);
                }
            }
            short8 ap[2];
#pragma unroll
            for (int tt = 0; tt < 2; ++tt)
                ap[tt] = *(const short8*)((const short*)(PuAll + (w * 2 + tt) * (16 * PST32)) +
                         l15 * (PST32 * 2) + quad * 8);
#pragma unroll
            for (int c = 0; c < 4; ++c)
#pragma unroll
                for (int tt = 0; tt < 2; ++tt)
                    numC[p * 2 + tt][c] = MFMA16(ap[tt], vh[c], numC[p * 2 + tt][c]);
        }
    }

#pragma unroll
    for (int t = 0; t < 4; ++t)
#pragma unroll
        for (int r = 0; r < 4; ++r) {
#pragma unroll
            for (int m = 1; m < 16; m <<= 1)
                dena[t][r] += __shfl_xor(dena[t][r], m, 64);
        }
    if (l15 == 0) {
#pragma unroll
        for (int t = 0; t < 4; ++t)
#pragma unroll
            for (int r = 0; r < 4; ++r)
                atomicAdd(&den[user0 + t * 16 + quad * 4 + r], dena[t][r]);
    }
#pragma unroll
    for (int t = 0; t < 4; ++t)
#pragma unroll
        for (int c = 0; c < 4; ++c)
#pragma unroll
            for (int r = 0; r < 4; ++r)
                atomicAdd(&num[(long)(user0 + t * 16 + quad * 4 + r) * DD + c * 16 + l15],
                          numC[t][c][r]);
}

// ---------------- K3: attn (0..784) | fill (785..1296) -----------------------
__global__ __launch_bounds__(256)
void k3_kernel(const unsigned short* __restrict__ Ubf,
               const unsigned short* __restrict__ Bbf,
               const unsigned short* __restrict__ ATbf,
               float* __restrict__ num, float* __restrict__ den,
               const int* __restrict__ irows, int* __restrict__ cur,
               int* __restrict__ eid)
{
    __shared__ __align__(16) unsigned int Pu[8][16 * PST32];
    int bid = blockIdx.x;
    if (bid < ATTN_BLOCKS) {
        attn_body(Ubf, Bbf, ATbf, num, den, &Pu[0][0], bid);
    } else {
        int lb = bid - ATTN_BLOCKS;
        for (int e = lb * 256 + threadIdx.x; e < NNZC; e += K3_FILL * 256) {
            int p = atomicAdd(&cur[irows[e]], 1);
            eid[p] = e;
        }
    }
}

// ---------------- K4: gather ALONE (unroll-4, 4 edge-chains in flight) -------
// Isolated from ent-agg: R9's K4 merge thrashed L2 (gather's A-matrix 2.5MB
// vs ent's 232MB random stream) -> 205us superadditive.
__global__ __launch_bounds__(256)
void gather_kernel(const int* __restrict__ offs, const int* __restrict__ eid,
                   const int* __restrict__ cols, const float* __restrict__ vals,
                   const float* __restrict__ A, float* __restrict__ seg)
{
    int w = threadIdx.x >> 6;
    int lane = threadIdx.x & 63;
    int u = blockIdx.x * 4 + w;          // grid 2500 -> u < 10000 always
    int s0 = offs[u], s1 = offs[u + 1];
    float a0 = 0.f, a1 = 0.f, a2 = 0.f, a3 = 0.f;
    int i = s0;
    for (; i + 3 < s1; i += 4) {
        int e0 = eid[i], e1 = eid[i + 1], e2 = eid[i + 2], e3 = eid[i + 3];
        float v0 = vals[e0], v1 = vals[e1], v2 = vals[e2], v3 = vals[e3];
        int c0 = cols[e0], c1 = cols[e1], c2 = cols[e2], c3 = cols[e3];
        a0 = fmaf(v0, A[(long)c0 * DD + lane], a0);
        a1 = fmaf(v1, A[(long)c1 * DD + lane], a1);
        a2 = fmaf(v2, A[(long)c2 * DD + lane], a2);
        a3 = fmaf(v3, A[(long)c3 * DD + lane], a3);
    }
    for (; i < s1; ++i) {
        int e = eid[i];
        a0 = fmaf(vals[e], A[(long)cols[e] * DD + lane], a0);
    }
    seg[(long)u * DD + lane] = (a0 + a1) + (a2 + a3);
}

// ---------------- K5: final (0..624) | entity agg 16 rows/block (625..6874) --
__global__ __launch_bounds__(256)
void k5_kernel(const float* __restrict__ seg, const float* __restrict__ num,
               const float* __restrict__ den, float* __restrict__ out_user,
               const float* __restrict__ ent_emb, const float* __restrict__ rel_emb,
               const int* __restrict__ neigh_entities, const int* __restrict__ neigh_relations,
               float* __restrict__ out_ent, int ent_blocks)
{
    int bid = blockIdx.x;
    if (bid < K5_FINAL) {
        int bse = (bid * 256 + threadIdx.x) * 4;
        int u = bse >> 6;
        float dv = den[u];
        float4 s = *(const float4*)(seg + bse);
        float4 n = *(const float4*)(num + bse);
        float4 o;
        o.x = fmaf(s.x, n.x / dv, s.x);
        o.y = fmaf(s.y, n.y / dv, s.y);
        o.z = fmaf(s.z, n.z / dv, s.z);
        o.w = fmaf(s.w, n.w / dv, s.w);
        *(float4*)(out_user + bse) = o;
    } else if (bid < K5_FINAL + ent_blocks) {
        int lb = bid - K5_FINAL;
        agg_body(ent_emb, ent_emb, rel_emb, neigh_entities, neigh_relations,
                 out_ent, 2 * lb);
        agg_body(ent_emb, ent_emb, rel_emb, neigh_entities, neigh_relations,
                 out_ent, 2 * lb + 1);
    }
}

// standalone pieces for the no-ws fallback (scratch aliases out_ent)
__global__ __launch_bounds__(256)
void agg_ent_kernel(const float* __restrict__ ent_emb, const float* __restrict__ rel_emb,
                    const int* __restrict__ ent_idx, const int* __restrict__ rel_idx,
                    float* __restrict__ outp)
{
    agg_body(ent_emb, ent_emb, rel_emb, ent_idx, rel_idx, outp, 2 * blockIdx.x);
    agg_body(ent_emb, ent_emb, rel_emb, ent_idx, rel_idx, outp, 2 * blockIdx.x + 1);
}

__global__ __launch_bounds__(256)
void final_kernel(const float* __restrict__ seg, const float* __restrict__ num,
                  const float* __restrict__ den, float* __restrict__ out, int n_users)
{
    int t = blockIdx.x * 256 + threadIdx.x;
    if (t >= n_users * DD) return;
    int u = t >> 6;
    float s = seg[t];
    float o2 = num[t] / den[u];
    out[t] = fmaf(s, o2, s);
}

extern "C" void kernel_launch(void* const* d_in, const int* in_sizes, int n_in,
                              void* d_out, int out_size, void* d_ws, size_t ws_size,
                              hipStream_t stream)
{
    const float* user_emb = (const float*)d_in[0];
    const float* news_emb = (const float*)d_in[1];
    const float* ent_emb  = (const float*)d_in[2];
    const float* rel_emb  = (const float*)d_in[3];
    const int* news_entities   = (const int*)d_in[4];
    const int* news_relations  = (const int*)d_in[5];
    const int* neigh_entities  = (const int*)d_in[6];
    const int* neigh_relations = (const int*)d_in[7];
    const int* interact_rows   = (const int*)d_in[8];
    const int* interact_cols   = (const int*)d_in[9];
    const float* interact_vals = (const float*)d_in[10];

    const int NU = 10000, NN = 10000, NE = 100000;

    float* out_news = (float*)d_out;
    float* out_ent  = out_news + (long)NN * DD;
    float* out_user = out_ent + (long)NE * DD;

    // Scratch ~11.15 MB: prefer d_ws, fall back to out_ent region
    const size_t BASIC_BYTES =
        (size_t)(640000 + 643072 + 10240 + 10240 + 10240 + 10240 + 500000) * 4 +
        (size_t)(643072 + 641024 + 641024) * 2;

    bool use_ws = (d_ws != nullptr) && (ws_size >= BASIC_BYTES);
    float* base = use_ws ? (float*)d_ws : out_ent;

    float* seg  = base;                              // 640000 f32
    float* num  = seg + 640000;                      // 643072 f32
    float* den  = num + 643072;                      // 10240 f32
    int*   cnt  = (int*)(den + 10240);               // 10240 i32
    int*   offs = cnt + 10240;                       // 10240 i32
    int*   cur  = offs + 10240;                      // 10240 i32
    int*   eid  = cur + 10240;                       // 500000 i32
    unsigned short* Ubf  = (unsigned short*)(eid + 500000);  // 643072 u16
    unsigned short* Bbf  = Ubf + 643072;             // 641024 u16
    unsigned short* ATbf = Bbf + 641024;             // 641024 u16

    // zero num | den | cnt (contiguous)
    hipMemsetAsync(num, 0, (size_t)(643072 + 10240 + 10240) * sizeof(float), stream);

    // K1: news agg | cvt U | hist
    k1_kernel<<<K1_GRID, 256, 0, stream>>>(news_emb, ent_emb, rel_emb,
                                           news_entities, news_relations, out_news,
                                           user_emb, Ubf, interact_rows, cnt);
    // K2: transpose+Bcvt | scan
    k2_kernel<<<80, 256, 0, stream>>>(out_news, Bbf, ATbf, cnt, offs, cur);
    // K3: attn | fill
    k3_kernel<<<K3_GRID, 256, 0, stream>>>(Ubf, Bbf, ATbf, num, den,
                                           interact_rows, cur, eid);
    // K4: gather alone
    gather_kernel<<<K4_GATHER, 256, 0, stream>>>(offs, eid, interact_cols,
                                                 interact_vals, out_news, seg);
    if (use_ws) {
        // K5: final | entity agg
        k5_kernel<<<K5_GRID, 256, 0, stream>>>(seg, num, den, out_user,
                                               ent_emb, rel_emb,
                                               neigh_entities, neigh_relations,
                                               out_ent, K5_ENT);
    } else {
        // Fallback (scratch aliases out_ent): entity agg must run LAST
        final_kernel<<<(NU * DD + 255) / 256, 256, 0, stream>>>(seg, num, den, out_user, NU);
        agg_ent_kernel<<<NE / 16, 256, 0, stream>>>(ent_emb, rel_emb,
                                                    neigh_entities, neigh_relations, out_ent);
    }
}

// Round 12
// 381.982 us; speedup vs baseline: 2.3776x; 1.1938x over previous
//
#include <hip/hip_runtime.h>
#include <hip/hip_bf16.h>

// All float tensors are fp32. R8 lesson: entity gathers MUST stay fp32
// (v^2->exp logit chain amplifies bf16 quantization to absmax 5.3).
// R10 lesson: NEVER fold the attn body into a multi-body persistent kernel
// (shared register frame spills the MFMA loop).
// R11 lesson: NEVER call agg_body twice in one kernel -- dual inline doubles
// the register frame (VGPR 64->92), residency 3->1.75 blocks/CU, 98.6->177us.
// The proven agg shape is ONE 8-row body call per 256-thread block.

#define DD 64
#define KK 20
#define NCHUNK 313        // ceil(10000/32) 32-news chunks
#define NSL 20            // news slices
#define NSTRIP 157        // 64-user strips / 4 MFMA tiles per wave (proven R4 shape)
#define ATSTRIDE 10016    // padded news stride of d-major V (interleaved 32-blocks)
#define PST32 20          // P LDS row stride in u32 (80 B)

#define NUC 10000
#define NNC 10000
#define NEC 100000
#define NNZC 500000

// K1: news agg (8 rows/block) | cvt U | hist
#define K1_NEWS 1250
#define K1_CVTU 628       // 643072/4/256
#define K1_HIST 512
#define K1_GRID (K1_NEWS + K1_CVTU + K1_HIST)
// K3: attn | fill
#define ATTN_BLOCKS 785   // 157*20/4
#define K3_FILL 512
#define K3_GRID (ATTN_BLOCKS + K3_FILL)
// K4: gather alone (R9 post-mortem: gather||ent thrashed L2 -> 205us superadditive)
#define K4_GATHER 2500
// K5: final | entity agg (8 rows/block)
#define K5_FINAL 625      // 640000 f32 = 625*256*4
#define K5_ENT 12500
#define K5_GRID (K5_FINAL + K5_ENT)

typedef __attribute__((ext_vector_type(8))) short short8;
typedef __attribute__((ext_vector_type(4))) float f32x4;

__device__ __forceinline__ unsigned short f2bf(float x) {
    union { __hip_bfloat16 h; unsigned short u; } cv;
    cv.h = __float2bfloat16(x);
    return cv.u;
}
__device__ __forceinline__ float bfu2f(unsigned short u) {
    return __uint_as_float(((unsigned)u) << 16);
}
#define MFMA16(a, b, c) __builtin_amdgcn_mfma_f32_16x16x32_bf16((a), (b), (c), 0, 0, 0)

// ---------------- aggregation body (8 rows per call), R2-proven shape --------
// TWO rows per wave: lanes 0-31 = row n0, lanes 32-63 = row n0+1; lane holds
// d = {2l, 2l+1} as float2. FP32 gathers only.
__device__ __forceinline__
void agg_body(const float* __restrict__ head_emb, const float* __restrict__ ent_emb,
              const float* __restrict__ rel_emb,
              const int* __restrict__ ent_idx, const int* __restrict__ rel_idx,
              float* __restrict__ outp, int bid)
{
    int w = threadIdx.x >> 6;
    int lane = threadIdx.x & 63;
    int half = lane >> 5;
    int l = lane & 31;
    int n0 = bid * 8 + w * 2;

    float2 head = *(const float2*)(head_emb + (long)(n0 + half) * DD + 2 * l);

    float2 tail[KK], trp[KK];
    float2 s2 = make_float2(0.f, 0.f);
#pragma unroll
    for (int k = 0; k < KK; ++k) {
        int ei0 = ent_idx[n0 * KK + k];
        int ei1 = ent_idx[(n0 + 1) * KK + k];
        int ri0 = rel_idx[n0 * KK + k];
        int ri1 = rel_idx[(n0 + 1) * KK + k];
        int e = half ? ei1 : ei0;
        int r = half ? ri1 : ri0;
        float2 rv = *(const float2*)(rel_emb + (long)r * DD + 2 * l);
        float2 tv = *(const float2*)(ent_emb + (long)e * DD + 2 * l);
        tail[k] = tv;
        trp[k] = make_float2(tv.x * rv.x, tv.y * rv.y);
        s2.x = fmaf(rv.x, rv.x, s2.x);
        s2.y = fmaf(rv.y, rv.y, s2.y);
    }
    float2 hn;
    hn.x = fabsf(head.x) * sqrtf(s2.x);
    hn.y = fabsf(head.y) * sqrtf(s2.y);

    float att[KK];
#pragma unroll
    for (int k = 0; k < KK; ++k) {
        float v = fmaf(trp[k].y, hn.y, trp[k].x * hn.x);
#pragma unroll
        for (int m = 1; m < 32; m <<= 1)
            v += __shfl_xor(v, m, 64);
        att[k] = v * v;
    }
    float mx = att[0];
#pragma unroll
    for (int k = 1; k < KK; ++k) mx = fmaxf(mx, att[k]);
    float den = 0.f;
#pragma unroll
    for (int k = 0; k < KK; ++k) { att[k] = __expf(att[k] - mx); den += att[k]; }
    float inv = 1.f / den;
    float2 o = make_float2(0.f, 0.f);
#pragma unroll
    for (int k = 0; k < KK; ++k) {
        o.x = fmaf(att[k], tail[k].x, o.x);
        o.y = fmaf(att[k], tail[k].y, o.y);
    }
    o.x *= inv; o.y *= inv;
    *(float2*)(outp + (long)(n0 + half) * DD + 2 * l) = o;
}

// ---------------- K1: news agg (8 rows/block) | cvt U | hist -----------------
__global__ __launch_bounds__(256)
void k1_kernel(const float* __restrict__ news_emb, const float* __restrict__ ent_emb,
               const float* __restrict__ rel_emb,
               const int* __restrict__ news_entities, const int* __restrict__ news_relations,
               float* __restrict__ out_news,
               const float* __restrict__ user_emb, unsigned short* __restrict__ Ubf,
               const int* __restrict__ irows, int* __restrict__ cnt)
{
    int bid = blockIdx.x;
    if (bid < K1_NEWS) {
        agg_body(news_emb, ent_emb, rel_emb, news_entities, news_relations,
                 out_news, bid);
    } else if (bid < K1_NEWS + K1_CVTU) {
        int i = (bid - K1_NEWS) * 256 + threadIdx.x;
        int bse = i * 4;
        float4 v = make_float4(0.f, 0.f, 0.f, 0.f);
        if (bse + 3 < NUC * DD) v = *(const float4*)(user_emb + bse);
        ushort4 o;
        o.x = f2bf(v.x); o.y = f2bf(v.y); o.z = f2bf(v.z); o.w = f2bf(v.w);
        *(ushort4*)(Ubf + bse) = o;
    } else {
        int lb = bid - (K1_NEWS + K1_CVTU);
        for (int e = lb * 256 + threadIdx.x; e < NNZC; e += K1_HIST * 256)
            atomicAdd(&cnt[irows[e]], 1);
    }
}

// ---------------- K2: transpose+Bcvt (blocks 0..78) | scan (block 79) --------
__global__ __launch_bounds__(256)
void k2_kernel(const float* __restrict__ src, unsigned short* __restrict__ Bbf,
               unsigned short* __restrict__ AT,
               const int* __restrict__ cnt, int* __restrict__ offs, int* __restrict__ cur)
{
    __shared__ float T[128][65];
    __shared__ int ssum[256];
    int t = threadIdx.x;
    if (blockIdx.x < 79) {
        int nb = blockIdx.x * 128;
        const float4* s4 = (const float4*)src;
#pragma unroll
        for (int i = 0; i < 8; ++i) {
            int f = i * 256 + t;
            int row = f >> 4;
            int c4 = f & 15;
            int gr = nb + row;
            float4 v = make_float4(0.f, 0.f, 0.f, 0.f);
            if (gr < NNC) v = s4[(long)gr * 16 + c4];
            T[row][c4 * 4 + 0] = v.x;
            T[row][c4 * 4 + 1] = v.y;
            T[row][c4 * 4 + 2] = v.z;
            T[row][c4 * 4 + 3] = v.w;
        }
        __syncthreads();
        // B rows (bf16 row-major, pad to 10016)
#pragma unroll
        for (int i = 0; i < 8; ++i) {
            int f = i * 256 + t;
            int row = f >> 4;
            int q4 = f & 15;
            int gr = nb + row;
            if (gr < ATSTRIDE) {
                ushort4 ob;
                ob.x = f2bf(T[row][q4 * 4 + 0]);
                ob.y = f2bf(T[row][q4 * 4 + 1]);
                ob.z = f2bf(T[row][q4 * 4 + 2]);
                ob.w = f2bf(T[row][q4 * 4 + 3]);
                *(ushort4*)(Bbf + (long)gr * 64 + q4 * 4) = ob;
            }
        }
        // AT interleaved: map {2g, 16+2g, 2g+1, 16+2g+1} within each 32-block
        int d = t >> 2;
        int seg = t & 3;
#pragma unroll
        for (int g = 0; g < 8; ++g) {
            int nl = seg * 32 + g * 4;
            int n = nb + nl;
            if (n + 3 < ATSTRIDE) {
                int base = seg * 32;
                ushort4 oh;
                oh.x = f2bf(T[base + 2 * g][d]);
                oh.y = f2bf(T[base + 16 + 2 * g][d]);
                oh.z = f2bf(T[base + 2 * g + 1][d]);
                oh.w = f2bf(T[base + 16 + 2 * g + 1][d]);
                *(ushort4*)(AT + (long)d * ATSTRIDE + n) = oh;
            }
        }
    } else {
        // scan: 256 threads x 40 rows = 10240 >= 10001 needed
        int loc[40];
        int s = 0;
#pragma unroll
        for (int i = 0; i < 40; ++i) { loc[i] = s; s += cnt[t * 40 + i]; }
        ssum[t] = s;
        __syncthreads();
        int val = s;
        for (int off = 1; off < 256; off <<= 1) {
            int v = (t >= off) ? ssum[t - off] : 0;
            __syncthreads();
            val += v;
            ssum[t] = val;
            __syncthreads();
        }
        int excl = val - s;
#pragma unroll
        for (int i = 0; i < 40; ++i) {
            int o = excl + loc[i];
            offs[t * 40 + i] = o;
            cur[t * 40 + i] = o;
        }
    }
}

// ---------------- attn body: R4-proven (98.9us), 64 users/wave ---------------
__device__ __forceinline__
void attn_body(const unsigned short* __restrict__ Ubf,
               const unsigned short* __restrict__ Bbf,
               const unsigned short* __restrict__ ATbf,
               float* __restrict__ num, float* __restrict__ den,
               unsigned int* __restrict__ PuAll, int bid)
{
    int w = threadIdx.x >> 6;
    int lane = threadIdx.x & 63;
    int quad = lane >> 4;
    int l15 = lane & 15;
    int wid = bid * 4 + w;
    int strip = wid % NSTRIP;
    int slice = wid / NSTRIP;
    int user0 = strip * 64;

    short8 ua0[4], ua1[4];
#pragma unroll
    for (int t = 0; t < 4; ++t) {
        const short* up = (const short*)Ubf + ((long)(user0 + t * 16 + l15)) * 64;
        ua0[t] = *(const short8*)(up + quad * 8);
        ua1[t] = *(const short8*)(up + 32 + quad * 8);
    }

    f32x4 numC[4][4];
    float dena[4][4];
#pragma unroll
    for (int t = 0; t < 4; ++t)
#pragma unroll
        for (int c = 0; c < 4; ++c) {
            numC[t][c] = (f32x4){0.f, 0.f, 0.f, 0.f};
            dena[t][c] = 0.f;
        }

    for (int ch = slice; ch < NCHUNK; ch += NSL) {
        int nb = ch * 32;
        const short* bh = (const short*)Bbf + ((long)(nb + l15)) * 64;
        short8 b00 = *(const short8*)(bh + quad * 8);
        short8 b01 = *(const short8*)(bh + 32 + quad * 8);
        short8 b10 = *(const short8*)(bh + 16 * 64 + quad * 8);
        short8 b11 = *(const short8*)(bh + 16 * 64 + 32 + quad * 8);

        short8 vh[4];
#pragma unroll
        for (int c = 0; c < 4; ++c)
            vh[c] = *(const short8*)((const short*)ATbf +
                    ((long)(16 * c + l15)) * ATSTRIDE + nb + quad * 8);

        bool vlo = (nb + l15) < NNC;
        bool vhi = (nb + 16 + l15) < NNC;
        f32x4 z = {0.f, 0.f, 0.f, 0.f};
#pragma unroll
        for (int p = 0; p < 2; ++p) {
#pragma unroll
            for (int tt = 0; tt < 2; ++tt) {
                int t = p * 2 + tt;
                f32x4 Llo = MFMA16(ua0[t], b00, z);
                Llo = MFMA16(ua1[t], b01, Llo);
                f32x4 Lhi = MFMA16(ua0[t], b10, z);
                Lhi = MFMA16(ua1[t], b11, Lhi);
                unsigned int* Pt = PuAll + (w * 2 + tt) * (16 * PST32);
#pragma unroll
                for (int r = 0; r < 4; ++r) {
                    float plo = vlo ? __expf(fminf(Llo[r], 70.f)) : 0.f;
                    float phi = vhi ? __expf(fminf(Lhi[r], 70.f)) : 0.f;
                    __hip_bfloat162 pk2 = __float22bfloat162_rn(make_float2(plo, phi));
                    unsigned int pk;
                    __builtin_memcpy(&pk, &pk2, 4);
                    Pt[(quad * 4 + r) * PST32 + l15] = pk;
                    dena[t][r] += __uint_as_float(pk << 16)
                                + __uint_as_float(pk & 0xffff0000u);
                }
            }
            short8 ap[2];
#pragma unroll
            for (int tt = 0; tt < 2; ++tt)
                ap[tt] = *(const short8*)((const short*)(PuAll + (w * 2 + tt) * (16 * PST32)) +
                         l15 * (PST32 * 2) + quad * 8);
#pragma unroll
            for (int c = 0; c < 4; ++c)
#pragma unroll
                for (int tt = 0; tt < 2; ++tt)
                    numC[p * 2 + tt][c] = MFMA16(ap[tt], vh[c], numC[p * 2 + tt][c]);
        }
    }

#pragma unroll
    for (int t = 0; t < 4; ++t)
#pragma unroll
        for (int r = 0; r < 4; ++r) {
#pragma unroll
            for (int m = 1; m < 16; m <<= 1)
                dena[t][r] += __shfl_xor(dena[t][r], m, 64);
        }
    if (l15 == 0) {
#pragma unroll
        for (int t = 0; t < 4; ++t)
#pragma unroll
            for (int r = 0; r < 4; ++r)
                atomicAdd(&den[user0 + t * 16 + quad * 4 + r], dena[t][r]);
    }
#pragma unroll
    for (int t = 0; t < 4; ++t)
#pragma unroll
        for (int c = 0; c < 4; ++c)
#pragma unroll
            for (int r = 0; r < 4; ++r)
                atomicAdd(&num[(long)(user0 + t * 16 + quad * 4 + r) * DD + c * 16 + l15],
                          numC[t][c][r]);
}

// ---------------- K3: attn (0..784) | fill (785..1296) -----------------------
__global__ __launch_bounds__(256)
void k3_kernel(const unsigned short* __restrict__ Ubf,
               const unsigned short* __restrict__ Bbf,
               const unsigned short* __restrict__ ATbf,
               float* __restrict__ num, float* __restrict__ den,
               const int* __restrict__ irows, int* __restrict__ cur,
               int* __restrict__ eid)
{
    __shared__ __align__(16) unsigned int Pu[8][16 * PST32];
    int bid = blockIdx.x;
    if (bid < ATTN_BLOCKS) {
        attn_body(Ubf, Bbf, ATbf, num, den, &Pu[0][0], bid);
    } else {
        int lb = bid - ATTN_BLOCKS;
        for (int e = lb * 256 + threadIdx.x; e < NNZC; e += K3_FILL * 256) {
            int p = atomicAdd(&cur[irows[e]], 1);
            eid[p] = e;
        }
    }
}

// ---------------- K4: gather ALONE (unroll-4, 4 edge-chains in flight) -------
__global__ __launch_bounds__(256)
void gather_kernel(const int* __restrict__ offs, const int* __restrict__ eid,
                   const int* __restrict__ cols, const float* __restrict__ vals,
                   const float* __restrict__ A, float* __restrict__ seg)
{
    int w = threadIdx.x >> 6;
    int lane = threadIdx.x & 63;
    int u = blockIdx.x * 4 + w;          // grid 2500 -> u < 10000 always
    int s0 = offs[u], s1 = offs[u + 1];
    float a0 = 0.f, a1 = 0.f, a2 = 0.f, a3 = 0.f;
    int i = s0;
    for (; i + 3 < s1; i += 4) {
        int e0 = eid[i], e1 = eid[i + 1], e2 = eid[i + 2], e3 = eid[i + 3];
        float v0 = vals[e0], v1 = vals[e1], v2 = vals[e2], v3 = vals[e3];
        int c0 = cols[e0], c1 = cols[e1], c2 = cols[e2], c3 = cols[e3];
        a0 = fmaf(v0, A[(long)c0 * DD + lane], a0);
        a1 = fmaf(v1, A[(long)c1 * DD + lane], a1);
        a2 = fmaf(v2, A[(long)c2 * DD + lane], a2);
        a3 = fmaf(v3, A[(long)c3 * DD + lane], a3);
    }
    for (; i < s1; ++i) {
        int e = eid[i];
        a0 = fmaf(vals[e], A[(long)cols[e] * DD + lane], a0);
    }
    seg[(long)u * DD + lane] = (a0 + a1) + (a2 + a3);
}

// ---------------- K5: final (0..624) | entity agg 8 rows/block (625..13124) --
__global__ __launch_bounds__(256)
void k5_kernel(const float* __restrict__ seg, const float* __restrict__ num,
               const float* __restrict__ den, float* __restrict__ out_user,
               const float* __restrict__ ent_emb, const float* __restrict__ rel_emb,
               const int* __restrict__ neigh_entities, const int* __restrict__ neigh_relations,
               float* __restrict__ out_ent, int ent_blocks)
{
    int bid = blockIdx.x;
    if (bid < K5_FINAL) {
        int bse = (bid * 256 + threadIdx.x) * 4;
        int u = bse >> 6;
        float dv = den[u];
        float4 s = *(const float4*)(seg + bse);
        float4 n = *(const float4*)(num + bse);
        float4 o;
        o.x = fmaf(s.x, n.x / dv, s.x);
        o.y = fmaf(s.y, n.y / dv, s.y);
        o.z = fmaf(s.z, n.z / dv, s.z);
        o.w = fmaf(s.w, n.w / dv, s.w);
        *(float4*)(out_user + bse) = o;
    } else if (bid < K5_FINAL + ent_blocks) {
        agg_body(ent_emb, ent_emb, rel_emb, neigh_entities, neigh_relations,
                 out_ent, bid - K5_FINAL);
    }
}

// standalone pieces for the no-ws fallback (scratch aliases out_ent)
__global__ __launch_bounds__(256)
void agg_ent_kernel(const float* __restrict__ ent_emb, const float* __restrict__ rel_emb,
                    const int* __restrict__ ent_idx, const int* __restrict__ rel_idx,
                    float* __restrict__ outp)
{
    agg_body(ent_emb, ent_emb, rel_emb, ent_idx, rel_idx, outp, blockIdx.x);
}

__global__ __launch_bounds__(256)
void final_kernel(const float* __restrict__ seg, const float* __restrict__ num,
                  const float* __restrict__ den, float* __restrict__ out, int n_users)
{
    int t = blockIdx.x * 256 + threadIdx.x;
    if (t >= n_users * DD) return;
    int u = t >> 6;
    float s = seg[t];
    float o2 = num[t] / den[u];
    out[t] = fmaf(s, o2, s);
}

extern "C" void kernel_launch(void* const* d_in, const int* in_sizes, int n_in,
                              void* d_out, int out_size, void* d_ws, size_t ws_size,
                              hipStream_t stream)
{
    const float* user_emb = (const float*)d_in[0];
    const float* news_emb = (const float*)d_in[1];
    const float* ent_emb  = (const float*)d_in[2];
    const float* rel_emb  = (const float*)d_in[3];
    const int* news_entities   = (const int*)d_in[4];
    const int* news_relations  = (const int*)d_in[5];
    const int* neigh_entities  = (const int*)d_in[6];
    const int* neigh_relations = (const int*)d_in[7];
    const int* interact_rows   = (const int*)d_in[8];
    const int* interact_cols   = (const int*)d_in[9];
    const float* interact_vals = (const float*)d_in[10];

    const int NU = 10000, NN = 10000, NE = 100000;

    float* out_news = (float*)d_out;
    float* out_ent  = out_news + (long)NN * DD;
    float* out_user = out_ent + (long)NE * DD;

    // Scratch ~11.15 MB: prefer d_ws, fall back to out_ent region
    const size_t BASIC_BYTES =
        (size_t)(640000 + 643072 + 10240 + 10240 + 10240 + 10240 + 500000) * 4 +
        (size_t)(643072 + 641024 + 641024) * 2;

    bool use_ws = (d_ws != nullptr) && (ws_size >= BASIC_BYTES);
    float* base = use_ws ? (float*)d_ws : out_ent;

    float* seg  = base;                              // 640000 f32
    float* num  = seg + 640000;                      // 643072 f32
    float* den  = num + 643072;                      // 10240 f32
    int*   cnt  = (int*)(den + 10240);               // 10240 i32
    int*   offs = cnt + 10240;                       // 10240 i32
    int*   cur  = offs + 10240;                      // 10240 i32
    int*   eid  = cur + 10240;                       // 500000 i32
    unsigned short* Ubf  = (unsigned short*)(eid + 500000);  // 643072 u16
    unsigned short* Bbf  = Ubf + 643072;             // 641024 u16
    unsigned short* ATbf = Bbf + 641024;             // 641024 u16

    // zero num | den | cnt (contiguous)
    hipMemsetAsync(num, 0, (size_t)(643072 + 10240 + 10240) * sizeof(float), stream);

    // K1: news agg | cvt U | hist
    k1_kernel<<<K1_GRID, 256, 0, stream>>>(news_emb, ent_emb, rel_emb,
                                           news_entities, news_relations, out_news,
                                           user_emb, Ubf, interact_rows, cnt);
    // K2: transpose+Bcvt | scan
    k2_kernel<<<80, 256, 0, stream>>>(out_news, Bbf, ATbf, cnt, offs, cur);
    // K3: attn | fill
    k3_kernel<<<K3_GRID, 256, 0, stream>>>(Ubf, Bbf, ATbf, num, den,
                                           interact_rows, cur, eid);
    // K4: gather alone
    gather_kernel<<<K4_GATHER, 256, 0, stream>>>(offs, eid, interact_cols,
                                                 interact_vals, out_news, seg);
    if (use_ws) {
        // K5: final | entity agg (8 rows/block)
        k5_kernel<<<K5_GRID, 256, 0, stream>>>(seg, num, den, out_user,
                                               ent_emb, rel_emb,
                                               neigh_entities, neigh_relations,
                                               out_ent, K5_ENT);
    } else {
        // Fallback (scratch aliases out_ent): entity agg must run LAST
        final_kernel<<<(NU * DD + 255) / 256, 256, 0, stream>>>(seg, num, den, out_user, NU);
        agg_ent_kernel<<<NE / 8, 256, 0, stream>>>(ent_emb, rel_emb,
                                                   neigh_entities, neigh_relations, out_ent);
    }
}